// Round 11
// baseline (1419.491 us; speedup 1.0000x reference)
//
#include <hip/hip_runtime.h>
#include <hip/hip_bf16.h>
#include <math.h>

#define TT 4
#define BB 8
#define MM 1024
#define HH 768
#define NHEAD 12
#define HDIM 64
#define NTOK 8192
#define H3 2304
#define H4 3072

typedef __attribute__((ext_vector_type(8))) short bf16x8;
typedef __attribute__((ext_vector_type(4))) float f32x4;
typedef __attribute__((ext_vector_type(4))) unsigned short u16x4;

#define GLOBAL_AS(p) ((const __attribute__((address_space(1))) void*)(p))
#define LDS_AS(p)    ((__attribute__((address_space(3))) void*)(p))

__device__ __forceinline__ unsigned short f2bf(float f) {
  union { float f; unsigned u; } v; v.f = f;
  unsigned r = v.u + 0x7fffu + ((v.u >> 16) & 1u);
  return (unsigned short)(r >> 16);
}

__device__ __forceinline__ unsigned cvt_pk_bf16(float lo, float hi) {
  unsigned r;
  asm("v_cvt_pk_bf16_f32 %0, %1, %2" : "=v"(r) : "v"(lo), "v"(hi));
  return r;
}

__device__ __forceinline__ float max3f(float a, float b, float c) {
  float r;
  asm("v_max3_f32 %0, %1, %2, %3" : "=v"(r) : "v"(a), "v"(b), "v"(c));
  return r;
}

__device__ __forceinline__ float fast_exp2(float x) {
#if __has_builtin(__builtin_amdgcn_exp2f)
  return __builtin_amdgcn_exp2f(x);
#else
  return exp2f(x);
#endif
}

__device__ __forceinline__ f32x4 mfma16(bf16x8 a, bf16x8 b, f32x4 c) {
  return __builtin_amdgcn_mfma_f32_16x16x32_bf16(a, b, c, 0, 0, 0);
}

__device__ __forceinline__ float block_sum256(float v, float* sh) {
  #pragma unroll
  for (int off = 32; off > 0; off >>= 1) v += __shfl_down(v, off);
  if ((threadIdx.x & 63) == 0) sh[threadIdx.x >> 6] = v;
  __syncthreads();
  v = sh[0] + sh[1] + sh[2] + sh[3];
  __syncthreads();
  return v;
}

__device__ __forceinline__ float block_max256(float v, float* sh) {
  #pragma unroll
  for (int off = 32; off > 0; off >>= 1) v = fmaxf(v, __shfl_down(v, off));
  if ((threadIdx.x & 63) == 0) sh[threadIdx.x >> 6] = v;
  __syncthreads();
  v = fmaxf(fmaxf(sh[0], sh[1]), fmaxf(sh[2], sh[3]));
  __syncthreads();
  return v;
}

// ---------------- weight convert + transpose: W[K][N] fp32 -> Wt[N][K] bf16
__global__ __launch_bounds__(256) void wconv_kernel(const float* __restrict__ W,
                                                    unsigned short* __restrict__ Wt,
                                                    int K, int N) {
  __shared__ float tile[32][33];
  const int n0 = blockIdx.x * 32, k0 = blockIdx.y * 32;
  const int tx = threadIdx.x, ty = threadIdx.y;
  #pragma unroll
  for (int j = 0; j < 4; j++)
    tile[ty + j*8][tx] = W[(size_t)(k0 + ty + j*8) * N + n0 + tx];
  __syncthreads();
  #pragma unroll
  for (int j = 0; j < 4; j++)
    Wt[(size_t)(n0 + ty + j*8) * K + k0 + tx] = f2bf(tile[tx][ty + j*8]);
}

// ---------------- LayerNorm: x fp32 [rows][768] -> bf16 out
__global__ __launch_bounds__(256) void ln_kernel(const float* __restrict__ x,
                                                 const float* __restrict__ s,
                                                 const float* __restrict__ b,
                                                 unsigned short* __restrict__ out) {
  __shared__ float sh[4];
  const int row = blockIdx.x;
  const int tid = threadIdx.x;
  const float* xr = x + (size_t)row * HH;
  float v[3];
  float sum = 0.f;
  #pragma unroll
  for (int j = 0; j < 3; j++) { v[j] = xr[tid + j*256]; sum += v[j]; }
  sum = block_sum256(sum, sh);
  const float mu = sum * (1.f/768.f);
  float ss = 0.f;
  #pragma unroll
  for (int j = 0; j < 3; j++) { float d = v[j] - mu; ss += d*d; }
  ss = block_sum256(ss, sh);
  const float rstd = rsqrtf(ss * (1.f/768.f) + 1e-5f);
  #pragma unroll
  for (int j = 0; j < 3; j++) {
    int col = tid + j*256;
    out[(size_t)row * HH + col] = f2bf((v[j]-mu)*rstd*s[col] + b[col]);
  }
}

// ---------------- 128^2 2-phase GEMM (all four GEMM shapes; proven fastest structure)
template<int EPI>
__global__ __launch_bounds__(256) void gemm_kernel(const unsigned short* __restrict__ A,
                                                   const unsigned short* __restrict__ Bt,
                                                   unsigned short* __restrict__ outB,
                                                   float* __restrict__ outF,
                                                   const float* __restrict__ bias,
                                                   int Ng, int Kg, int nx) {
  __shared__ unsigned short a_lds[2][128*64];
  __shared__ unsigned short b_lds[2][128*64];
  const int tid = threadIdx.x;
  const int w = tid >> 6, l = tid & 63;
  const int nwg = gridDim.x;
  const int lin = blockIdx.x;
  const int L = (lin & 7) * (nwg >> 3) + (lin >> 3);
  const int m0 = (L / nx) * 128, n0 = (L % nx) * 128;

  const int wr = (w >> 1) * 64, wc = (w & 1) * 64;
  const int l15 = l & 15, lhi = l >> 4;
  const int srow = w*32 + (l >> 3);
  const int schunk = (l & 7) ^ (l >> 3);
  const int scol = schunk << 3;

  f32x4 acc[4][4] = {};
  const int nk = Kg >> 6;
  int cur = 0;

  #pragma unroll
  for (int i = 0; i < 4; i++) {
    const unsigned short* gsa = A  + (size_t)(m0 + srow + i*8)*Kg + scol;
    const unsigned short* gsb = Bt + (size_t)(n0 + srow + i*8)*Kg + scol;
    __builtin_amdgcn_global_load_lds(GLOBAL_AS(gsa), LDS_AS(&a_lds[0][w*2048 + i*512]), 16, 0, 0);
    __builtin_amdgcn_global_load_lds(GLOBAL_AS(gsb), LDS_AS(&b_lds[0][w*2048 + i*512]), 16, 0, 0);
  }
  __syncthreads();

  for (int t = 0; t < nk; t++) {
    if (t + 1 < nk) {
      const int ks = (t + 1) << 6;
      #pragma unroll
      for (int i = 0; i < 4; i++) {
        const unsigned short* gsa = A  + (size_t)(m0 + srow + i*8)*Kg + ks + scol;
        const unsigned short* gsb = Bt + (size_t)(n0 + srow + i*8)*Kg + ks + scol;
        __builtin_amdgcn_global_load_lds(GLOBAL_AS(gsa), LDS_AS(&a_lds[cur^1][w*2048 + i*512]), 16, 0, 0);
        __builtin_amdgcn_global_load_lds(GLOBAL_AS(gsb), LDS_AS(&b_lds[cur^1][w*2048 + i*512]), 16, 0, 0);
      }
    }
    const unsigned short* ab = &a_lds[cur][0];
    const unsigned short* bb = &b_lds[cur][0];
    #pragma unroll
    for (int kb = 0; kb < 2; kb++) {
      bf16x8 af[4], bfr[4];
      const int rc = (kb*4 + lhi) ^ (l15 & 7);
      #pragma unroll
      for (int rb = 0; rb < 4; rb++)
        af[rb] = *(const bf16x8*)&ab[(wr + rb*16 + l15)*64 + (rc << 3)];
      #pragma unroll
      for (int nb = 0; nb < 4; nb++)
        bfr[nb] = *(const bf16x8*)&bb[(wc + nb*16 + l15)*64 + (rc << 3)];
      #pragma unroll
      for (int rb = 0; rb < 4; rb++)
        #pragma unroll
        for (int nb = 0; nb < 4; nb++)
          acc[rb][nb] = mfma16(af[rb], bfr[nb], acc[rb][nb]);
    }
    __syncthreads();
    cur ^= 1;
  }

  const int lr = lhi << 2;
  #pragma unroll
  for (int rb = 0; rb < 4; rb++)
    #pragma unroll
    for (int nb = 0; nb < 4; nb++) {
      const int row = m0 + wr + rb*16 + lr;
      const int col = n0 + wc + nb*16 + l15;
      #pragma unroll
      for (int r = 0; r < 4; r++) {
        float v = acc[rb][nb][r];
        const size_t off = (size_t)(row + r)*Ng + col;
        if (EPI == 0) {
          outB[off] = f2bf(v);
        } else if (EPI == 1) {
          v += bias[col];
          float u = 0.79788456080287f * v * (1.f + 0.044715f * v * v);
          u = fminf(u, 15.f);
          float e = fast_exp2(u * 2.88539008177793f);
          float th = 1.f - 2.f / (e + 1.f);
          v = 0.5f * v * (1.f + th);
          outB[off] = f2bf(v);
        } else {
          v += bias[col] + outF[off];
          outF[off] = v;
        }
      }
    }
}

// ---------------- bias precompute: biasP[b][q][k] = log2e*(ov_emb[min(ov,10)] - alpha*clip(lp[b][k]))
__global__ __launch_bounds__(256) void biasprep_kernel(const int* __restrict__ overlap,
                                                       const float* __restrict__ lp,
                                                       const float* __restrict__ ov_emb,
                                                       const float* __restrict__ ht_alpha,
                                                       float* __restrict__ biasP) {
  __shared__ float oe[11];
  if (threadIdx.x < 11) oe[threadIdx.x] = ov_emb[threadIdx.x] * 1.44269504088896f;
  __syncthreads();
  const float aL = ht_alpha[0] * 1.44269504088896f;
  const size_t base = ((size_t)blockIdx.x * 256 + threadIdx.x) * 4;
  const int b = (int)(base >> 20);
  const int k0 = (int)(base & 1023);
  int4 ov = *(const int4*)&overlap[base];
  float4 lv = *(const float4*)&lp[b * MM + k0];
  float4 o4;
  {
    int t0 = ov.x < 10 ? ov.x : 10; float c0 = fminf(fmaxf(lv.x, -30.f), 0.f); o4.x = oe[t0] - aL*c0;
    int t1 = ov.y < 10 ? ov.y : 10; float c1 = fminf(fmaxf(lv.y, -30.f), 0.f); o4.y = oe[t1] - aL*c1;
    int t2 = ov.z < 10 ? ov.z : 10; float c2 = fminf(fmaxf(lv.z, -30.f), 0.f); o4.z = oe[t2] - aL*c2;
    int t3 = ov.w < 10 ? ov.w : 10; float c3 = fminf(fmaxf(lv.w, -30.f), 0.f); o4.w = oe[t3] - aL*c3;
  }
  *(float4*)&biasP[base] = o4;
}

// ---------------- flash attention, swapped operands (S^T / O^T), exp2-domain softmax
// R5 structure (single barrier/kt, dbuf K+V, 48KB LDS) + rotated bias prefetch
// (bregs(kt+1) issued right after kt's bias-consume -> ~full iteration of latency
// cover) + max3/tree reductions for the softmax serial chain. Grid-limited at
// 3 blocks/CU, so extra VGPR live range is free (<=168 keeps 3 waves/SIMD).
__global__ __launch_bounds__(256) void attn_kernel(const unsigned short* __restrict__ qkv,
                                                   const float* __restrict__ biasP,
                                                   unsigned short* __restrict__ obuf) {
  __shared__ unsigned short k_lds[2][64*64];
  __shared__ unsigned short v_lds[2][64*64];
  __shared__ unsigned short pmat[4][32*64];

  const int tid = threadIdx.x;
  const int w = tid >> 6, l = tid & 63;
  const int lin = blockIdx.x;
  const int L = (lin & 7) * 96 + (lin >> 3);    // bijective (768 % 8 == 0)
  const int h = L % 12;
  const int qb = (L / 12) & 7;
  const int b = L / 96;
  const int q0w = qb*128 + w*32;
  const int l15 = l & 15, lhi = l >> 4;
  const float SC = 0.125f * 1.44269504088896f;

  const int kr_s = l >> 3;
  const int schunk = (l & 7) ^ kr_s;
  const int dc = (l & 7) << 3;

  bf16x8 qf[2][2];
  #pragma unroll
  for (int rb = 0; rb < 2; rb++)
    #pragma unroll
    for (int kb = 0; kb < 2; kb++)
      qf[rb][kb] = *(const bf16x8*)&qkv[(size_t)(b*MM + q0w + rb*16 + l15)*H3 + h*HDIM + kb*32 + lhi*8];

  const float* brow[2];
  #pragma unroll
  for (int rb = 0; rb < 2; rb++)
    brow[rb] = biasP + (size_t)(b*MM + q0w + rb*16 + l15) * MM;

  f32x4 oacc[4][2] = {};
  float mrow[2] = {-INFINITY, -INFINITY};
  float lrow[2] = {0.f, 0.f};

  // prologue: K0 -> LDS, V0 -> LDS (via regs), V1 -> vcur, bias(0) -> bregs
  bf16x8 vcur[2];
  f32x4 bregs[4][2];
  {
    #pragma unroll
    for (int i = 0; i < 2; i++) {
      const unsigned short* g = qkv + (size_t)(b*MM + i*32 + w*8 + kr_s)*H3 + h*HDIM + HH + schunk*8;
      __builtin_amdgcn_global_load_lds(GLOBAL_AS(g), LDS_AS(&k_lds[0][(i*32 + w*8)*64]), 16, 0, 0);
    }
    bf16x8 vr[2];
    #pragma unroll
    for (int i = 0; i < 2; i++)
      vr[i] = *(const bf16x8*)&qkv[(size_t)(b*MM + i*32 + w*8 + kr_s)*H3 + h*HDIM + 2*HH + dc];
    #pragma unroll
    for (int i = 0; i < 2; i++) {
      int kr = i*32 + w*8 + kr_s;
      #pragma unroll
      for (int j = 0; j < 8; j++) {
        int key = ((((dc >> 3) & 7) ^ j) & 7) << 3;
        v_lds[0][(dc + j)*64 + (kr ^ key)] = (unsigned short)(short)vr[i][j];
      }
    }
    #pragma unroll
    for (int i = 0; i < 2; i++)
      vcur[i] = *(const bf16x8*)&qkv[(size_t)(b*MM + 64 + i*32 + w*8 + kr_s)*H3 + h*HDIM + 2*HH + dc];
    #pragma unroll
    for (int nb = 0; nb < 4; nb++)
      #pragma unroll
      for (int rb = 0; rb < 2; rb++)
        bregs[nb][rb] = *(const f32x4*)&brow[rb][nb*16 + lhi*4];
    __syncthreads();
  }

  for (int kt = 0; kt < 16; kt++) {
    const int cur = kt & 1;
    const int kbase = kt * 64;

    // top-of-iteration staging (buffers cur^1 freed by previous iter's barrier)
    if (kt < 15) {
      // write V(kt+1) from regs (loaded one full iteration ago)
      #pragma unroll
      for (int i = 0; i < 2; i++) {
        int kr = i*32 + w*8 + kr_s;
        #pragma unroll
        for (int j = 0; j < 8; j++) {
          int key = ((((dc >> 3) & 7) ^ j) & 7) << 3;
          v_lds[cur^1][(dc + j)*64 + (kr ^ key)] = (unsigned short)(short)vcur[i][j];
        }
      }
      // issue K(kt+1) async copy
      const int nbase = kbase + 64;
      #pragma unroll
      for (int i = 0; i < 2; i++) {
        const unsigned short* g = qkv + (size_t)(b*MM + nbase + i*32 + w*8 + kr_s)*H3 + h*HDIM + HH + schunk*8;
        __builtin_amdgcn_global_load_lds(GLOBAL_AS(g), LDS_AS(&k_lds[cur^1][(i*32 + w*8)*64]), 16, 0, 0);
      }
    }
    if (kt < 14) {
      const int n2 = kbase + 128;
      #pragma unroll
      for (int i = 0; i < 2; i++)
        vcur[i] = *(const bf16x8*)&qkv[(size_t)(b*MM + n2 + i*32 + w*8 + kr_s)*H3 + h*HDIM + 2*HH + dc];
    }

    // ---- S^T[kk][q] = K·Q^T
    f32x4 sacc[4][2] = {};
    __builtin_amdgcn_s_setprio(1);
    #pragma unroll
    for (int kb = 0; kb < 2; kb++) {
      bf16x8 ak[4];
      #pragma unroll
      for (int nb = 0; nb < 4; nb++) {
        int n = nb*16 + l15;
        ak[nb] = *(const bf16x8*)&k_lds[cur][n*64 + ((kb*32 + lhi*8) ^ ((n & 7) << 3))];
      }
      #pragma unroll
      for (int nb = 0; nb < 4; nb++)
        #pragma unroll
        for (int rb = 0; rb < 2; rb++)
          sacc[nb][rb] = mfma16(ak[nb], qf[rb][kb], sacc[nb][rb]);
    }
    __builtin_amdgcn_s_setprio(0);

    // scale (log2 domain) + bias (prefetched one iteration ago)
    #pragma unroll
    for (int nb = 0; nb < 4; nb++)
      #pragma unroll
      for (int rb = 0; rb < 2; rb++)
        #pragma unroll
        for (int r = 0; r < 4; r++)
          sacc[nb][rb][r] = fmaf(sacc[nb][rb][r], SC, bregs[nb][rb][r]);

    // rotated bias prefetch: issue bregs(kt+1) now; consumed next iteration,
    // so L2 latency hides under softmax + PV + barrier.
    if (kt < 15) {
      const int nb4 = kbase + 64;
      #pragma unroll
      for (int nb = 0; nb < 4; nb++)
        #pragma unroll
        for (int rb = 0; rb < 2; rb++)
          bregs[nb][rb] = *(const f32x4*)&brow[rb][nb4 + nb*16 + lhi*4];
    }

    // lane-local online softmax with defer-max; max3-tree + pairwise-sum-tree
    float corrf[2];
    int defer[2];
    #pragma unroll
    for (int rb = 0; rb < 2; rb++) {
      const f32x4 s0 = sacc[0][rb], s1 = sacc[1][rb], s2 = sacc[2][rb], s3 = sacc[3][rb];
      float t0 = max3f(s0[0], s0[1], s0[2]);
      float t1 = max3f(s0[3], s1[0], s1[1]);
      float t2 = max3f(s1[2], s1[3], s2[0]);
      float t3 = max3f(s2[1], s2[2], s2[3]);
      float t4 = max3f(s3[0], s3[1], s3[2]);
      float pm = fmaxf(max3f(t0, t1, t2), max3f(t3, t4, s3[3]));
      pm = fmaxf(pm, __shfl_xor(pm, 16));
      pm = fmaxf(pm, __shfl_xor(pm, 32));
      defer[rb] = __all(pm - mrow[rb] <= 8.0f);
      const float mnew = defer[rb] ? mrow[rb] : fmaxf(mrow[rb], pm);
      const float corr = defer[rb] ? 1.0f : fast_exp2(mrow[rb] - mnew);
      #pragma unroll
      for (int nb = 0; nb < 4; nb++)
        #pragma unroll
        for (int r = 0; r < 4; r++)
          sacc[nb][rb][r] = fast_exp2(sacc[nb][rb][r] - mnew);
      // pairwise tree sum of the 16 probabilities
      float a0 = (sacc[0][rb][0] + sacc[0][rb][1]) + (sacc[0][rb][2] + sacc[0][rb][3]);
      float a1 = (sacc[1][rb][0] + sacc[1][rb][1]) + (sacc[1][rb][2] + sacc[1][rb][3]);
      float a2 = (sacc[2][rb][0] + sacc[2][rb][1]) + (sacc[2][rb][2] + sacc[2][rb][3]);
      float a3 = (sacc[3][rb][0] + sacc[3][rb][1]) + (sacc[3][rb][2] + sacc[3][rb][3]);
      float rs = (a0 + a1) + (a2 + a3);
      rs += __shfl_xor(rs, 16);
      rs += __shfl_xor(rs, 32);
      mrow[rb] = mnew;
      lrow[rb] = lrow[rb]*corr + rs;
      corrf[rb] = corr;
    }
    #pragma unroll
    for (int rb = 0; rb < 2; rb++)
      if (!defer[rb]) {          // wave-uniform branch
        #pragma unroll
        for (int db = 0; db < 4; db++)
          #pragma unroll
          for (int r = 0; r < 4; r++)
            oacc[db][rb][r] *= corrf[rb];
      }

    // P^T tile to per-wave LDS as [q][kk] (packed via cvt_pk)
    unsigned short* pw = &pmat[w][0];
    #pragma unroll
    for (int nb = 0; nb < 4; nb++)
      #pragma unroll
      for (int rb = 0; rb < 2; rb++) {
        uint2 pk;
        pk.x = cvt_pk_bf16(sacc[nb][rb][0], sacc[nb][rb][1]);
        pk.y = cvt_pk_bf16(sacc[nb][rb][2], sacc[nb][rb][3]);
        *(uint2*)&pw[(rb*16 + l15)*64 + ((nb*16 + lhi*4) ^ ((l15 & 7) << 3))] = pk;
      }

    // O^T += V^T · P^T
    __builtin_amdgcn_s_setprio(1);
    #pragma unroll
    for (int kb = 0; kb < 2; kb++) {
      bf16x8 pb[2];
      #pragma unroll
      for (int rb = 0; rb < 2; rb++)
        pb[rb] = *(const bf16x8*)&pw[(rb*16 + l15)*64 + ((kb*32 + lhi*8) ^ ((l15 & 7) << 3))];
      bf16x8 av[4];
      #pragma unroll
      for (int db = 0; db < 4; db++) {
        int d = db*16 + l15;
        int key = ((((d >> 3) & 7) ^ (d & 7)) & 7) << 3;
        av[db] = *(const bf16x8*)&v_lds[cur][d*64 + ((kb*32 + lhi*8) ^ key)];
      }
      #pragma unroll
      for (int db = 0; db < 4; db++)
        #pragma unroll
        for (int rb = 0; rb < 2; rb++)
          oacc[db][rb] = mfma16(av[db], pb[rb], oacc[db][rb]);
    }
    __builtin_amdgcn_s_setprio(0);

    __syncthreads();   // single barrier: drains K gload + V/bias reg loads; frees cur bufs
  }

  // epilogue: normalize, transpose via per-wave LDS, coalesced write
  float inv[2] = { 1.f / lrow[0], 1.f / lrow[1] };
  unsigned short* pw = &pmat[w][0];
  #pragma unroll
  for (int db = 0; db < 4; db++)
    #pragma unroll
    for (int rb = 0; rb < 2; rb++) {
      uint2 pk;
      pk.x = cvt_pk_bf16(oacc[db][rb][0] * inv[rb], oacc[db][rb][1] * inv[rb]);
      pk.y = cvt_pk_bf16(oacc[db][rb][2] * inv[rb], oacc[db][rb][3] * inv[rb]);
      *(uint2*)&pw[(rb*16 + l15)*64 + ((db*16 + lhi*4) ^ ((l15 & 7) << 3))] = pk;
    }
  #pragma unroll
  for (int rep = 0; rep < 4; rep++) {
    int qq = rep*8 + (l >> 3);
    int d0 = (l & 7) << 3;
    bf16x8 vv = *(const bf16x8*)&pw[qq*64 + (d0 ^ ((qq & 7) << 3))];
    *(bf16x8*)&obuf[(size_t)(b*MM + q0w + qq)*HH + h*HDIM + d0] = vv;
  }
}

// ---------------- HT weights
__global__ __launch_bounds__(256) void htw_kernel(const float* __restrict__ lp,
                                                  float* __restrict__ w_ht) {
  __shared__ float sh[4];
  const int b = blockIdx.x, tid = threadIdx.x;
  float vals[4];
  float mx = -INFINITY;
  #pragma unroll
  for (int j = 0; j < 4; j++) {
    float lv = lp[b*MM + tid + j*256];
    float lc = fminf(fmaxf(lv, -30.f), 0.f);
    vals[j] = -lc;
    mx = fmaxf(mx, vals[j]);
  }
  mx = block_max256(mx, sh);
  float se = 0.f;
  #pragma unroll
  for (int j = 0; j < 4; j++) { vals[j] = expf(vals[j] - mx); se += vals[j]; }
  se = block_sum256(se, sh);
  const float inv = 1.f / se;
  #pragma unroll
  for (int j = 0; j < 4; j++) w_ht[b*MM + tid + j*256] = vals[j] * inv;
}

// ---------------- final LN + weighted partial sums
__global__ __launch_bounds__(256) void final_partial_kernel(const float* __restrict__ xbuf,
                                                            const float* __restrict__ lno_s,
                                                            const float* __restrict__ lno_b,
                                                            const float* __restrict__ w_ht,
                                                            float* __restrict__ part) {
  __shared__ float sh[4];
  const int b = blockIdx.x >> 4;
  const int chunk = blockIdx.x & 15;
  const int tid = threadIdx.x;
  float acc[3] = {0.f, 0.f, 0.f};
  float sc[3], bc[3];
  #pragma unroll
  for (int j = 0; j < 3; j++) { sc[j] = lno_s[tid + j*256]; bc[j] = lno_b[tid + j*256]; }
  for (int rr = 0; rr < 64; rr++) {
    const int tok = b*MM + chunk*64 + rr;
    const float* xr = xbuf + (size_t)tok * HH;
    float v[3]; float sum = 0.f;
    #pragma unroll
    for (int j = 0; j < 3; j++) { v[j] = xr[tid + j*256]; sum += v[j]; }
    sum = block_sum256(sum, sh);
    const float mu = sum * (1.f/768.f);
    float ss = 0.f;
    #pragma unroll
    for (int j = 0; j < 3; j++) { float d = v[j] - mu; ss += d*d; }
    ss = block_sum256(ss, sh);
    const float rstd = rsqrtf(ss * (1.f/768.f) + 1e-5f);
    const float wgt = w_ht[b*MM + chunk*64 + rr];
    #pragma unroll
    for (int j = 0; j < 3; j++) acc[j] += wgt * ((v[j]-mu)*rstd*sc[j] + bc[j]);
  }
  #pragma unroll
  for (int j = 0; j < 3; j++) part[(size_t)blockIdx.x * HH + tid + j*256] = acc[j];
}

__global__ __launch_bounds__(256) void final_reduce_kernel(const float* __restrict__ part,
                                                           float* __restrict__ out) {
  const int b = blockIdx.x;
  const int col = blockIdx.y*256 + threadIdx.x;
  float s = 0.f;
  #pragma unroll
  for (int c = 0; c < 16; c++) s += part[(size_t)(b*16 + c) * HH + col];
  out[b*HH + col] = s;
}

extern "C" void kernel_launch(void* const* d_in, const int* in_sizes, int n_in,
                              void* d_out, int out_size, void* d_ws, size_t ws_size,
                              hipStream_t stream) {
  (void)in_sizes; (void)n_in;
  const float* x      = (const float*)d_in[0];
  const int*   overlap= (const int*)d_in[1];
  const float* lp     = (const float*)d_in[2];
  const float* ln1_s  = (const float*)d_in[3];
  const float* ln1_b  = (const float*)d_in[4];
  const float* Wqkv   = (const float*)d_in[5];
  const float* Wout   = (const float*)d_in[6];
  const float* bout   = (const float*)d_in[7];
  const float* ln2_s  = (const float*)d_in[8];
  const float* ln2_b  = (const float*)d_in[9];
  const float* W1     = (const float*)d_in[10];
  const float* b1     = (const float*)d_in[11];
  const float* W2     = (const float*)d_in[12];
  const float* b2     = (const float*)d_in[13];
  const float* lno_s  = (const float*)d_in[14];
  const float* lno_b  = (const float*)d_in[15];
  const float* ov_emb = (const float*)d_in[16];
  const float* ht_alpha = (const float*)d_in[17];
  float* out = (float*)d_out;

  char* ws = (char*)d_ws;
  float*          xbuf  = (float*)(ws + 0);                    // 25165824 B
  unsigned short* lnout = (unsigned short*)(ws + 25165824);    // 12582912 B
  unsigned short* qkv   = (unsigned short*)(ws + 37748736);    // 37748736 B
  unsigned short* obuf  = (unsigned short*)(ws + 75497472);    // 12582912 B
  unsigned short* gbuf  = (unsigned short*)(ws + 88080384);    // 50331648 B
  unsigned short* wbuf  = (unsigned short*)(ws + 138412032);   //  4718592 B
  float*          w_ht  = (float*)(ws + 143130624);            //    32768 B
  float*          part  = (float*)(ws + 143163392);            //   393216 B
  const int prep_once = (ws_size >= (size_t)143556608 + (size_t)33554432);
  float*          biasP = prep_once ? (float*)(ws + 143556608) : (float*)gbuf;

  hipMemcpyAsync(xbuf, x, (size_t)NTOK * HH * sizeof(float), hipMemcpyDeviceToDevice, stream);
  htw_kernel<<<BB, 256, 0, stream>>>(lp, w_ht);
  if (prep_once)
    biasprep_kernel<<<(BB*MM*MM/4)/256, 256, 0, stream>>>(overlap, lp, ov_emb, ht_alpha, biasP);

  for (int t = 0; t < TT; t++) {
    // --- attention block
    wconv_kernel<<<dim3(H3/32, HH/32), dim3(32, 8), 0, stream>>>(Wqkv + (size_t)t*HH*H3, wbuf, HH, H3);
    ln_kernel<<<NTOK, 256, 0, stream>>>(xbuf, ln1_s + t*HH, ln1_b + t*HH, lnout);
    gemm_kernel<0><<<(H3/128)*(NTOK/128), 256, 0, stream>>>(lnout, wbuf, qkv, nullptr, nullptr, H3, HH, H3/128);
    if (!prep_once)
      biasprep_kernel<<<(BB*MM*MM/4)/256, 256, 0, stream>>>(overlap, lp, ov_emb, ht_alpha, biasP);
    attn_kernel<<<BB*NHEAD*(MM/128), 256, 0, stream>>>(qkv, biasP, obuf);
    wconv_kernel<<<dim3(HH/32, HH/32), dim3(32, 8), 0, stream>>>(Wout + (size_t)t*HH*HH, wbuf, HH, HH);
    gemm_kernel<2><<<(HH/128)*(NTOK/128), 256, 0, stream>>>(obuf, wbuf, nullptr, xbuf, bout + t*HH, HH, HH, HH/128);
    // --- FFN block
    ln_kernel<<<NTOK, 256, 0, stream>>>(xbuf, ln2_s + t*HH, ln2_b + t*HH, lnout);
    wconv_kernel<<<dim3(H4/32, HH/32), dim3(32, 8), 0, stream>>>(W1 + (size_t)t*HH*H4, wbuf, HH, H4);
    gemm_kernel<1><<<(H4/128)*(NTOK/128), 256, 0, stream>>>(lnout, wbuf, gbuf, nullptr, b1 + t*H4, H4, HH, H4/128);
    wconv_kernel<<<dim3(HH/32, H4/32), dim3(32, 8), 0, stream>>>(W2 + (size_t)t*H4*HH, wbuf, H4, HH);
    gemm_kernel<2><<<(HH/128)*(NTOK/128), 256, 0, stream>>>(gbuf, wbuf, nullptr, xbuf, b2 + t*HH, HH, H4, HH/128);
  }

  final_partial_kernel<<<BB*16, 256, 0, stream>>>(xbuf, lno_s, lno_b, w_ht, part);
  final_reduce_kernel<<<dim3(BB, 3), 256, 0, stream>>>(part, out);

  (void)out_size;
}

// Round 12
// 1301.176 us; speedup vs baseline: 1.0909x; 1.0909x over previous
//
#include <hip/hip_runtime.h>
#include <hip/hip_bf16.h>
#include <math.h>

#define TT 4
#define BB 8
#define MM 1024
#define HH 768
#define NHEAD 12
#define HDIM 64
#define NTOK 8192
#define H3 2304
#define H4 3072

typedef __attribute__((ext_vector_type(8))) short bf16x8;
typedef __attribute__((ext_vector_type(4))) float f32x4;
typedef __attribute__((ext_vector_type(4))) unsigned short u16x4;

#define GLOBAL_AS(p) ((const __attribute__((address_space(1))) void*)(p))
#define LDS_AS(p)    ((__attribute__((address_space(3))) void*)(p))

__device__ __forceinline__ unsigned short f2bf(float f) {
  union { float f; unsigned u; } v; v.f = f;
  unsigned r = v.u + 0x7fffu + ((v.u >> 16) & 1u);
  return (unsigned short)(r >> 16);
}

__device__ __forceinline__ unsigned cvt_pk_bf16(float lo, float hi) {
  unsigned r;
  asm("v_cvt_pk_bf16_f32 %0, %1, %2" : "=v"(r) : "v"(lo), "v"(hi));
  return r;
}

__device__ __forceinline__ float fast_exp2(float x) {
#if __has_builtin(__builtin_amdgcn_exp2f)
  return __builtin_amdgcn_exp2f(x);
#else
  return exp2f(x);
#endif
}

__device__ __forceinline__ f32x4 mfma16(bf16x8 a, bf16x8 b, f32x4 c) {
  return __builtin_amdgcn_mfma_f32_16x16x32_bf16(a, b, c, 0, 0, 0);
}

__device__ __forceinline__ float block_sum256(float v, float* sh) {
  #pragma unroll
  for (int off = 32; off > 0; off >>= 1) v += __shfl_down(v, off);
  if ((threadIdx.x & 63) == 0) sh[threadIdx.x >> 6] = v;
  __syncthreads();
  v = sh[0] + sh[1] + sh[2] + sh[3];
  __syncthreads();
  return v;
}

__device__ __forceinline__ float block_max256(float v, float* sh) {
  #pragma unroll
  for (int off = 32; off > 0; off >>= 1) v = fmaxf(v, __shfl_down(v, off));
  if ((threadIdx.x & 63) == 0) sh[threadIdx.x >> 6] = v;
  __syncthreads();
  v = fmaxf(fmaxf(sh[0], sh[1]), fmaxf(sh[2], sh[3]));
  __syncthreads();
  return v;
}

// ---------------- weight convert + transpose: W[K][N] fp32 -> Wt[N][K] bf16
__global__ __launch_bounds__(256) void wconv_kernel(const float* __restrict__ W,
                                                    unsigned short* __restrict__ Wt,
                                                    int K, int N) {
  __shared__ float tile[32][33];
  const int n0 = blockIdx.x * 32, k0 = blockIdx.y * 32;
  const int tx = threadIdx.x, ty = threadIdx.y;
  #pragma unroll
  for (int j = 0; j < 4; j++)
    tile[ty + j*8][tx] = W[(size_t)(k0 + ty + j*8) * N + n0 + tx];
  __syncthreads();
  #pragma unroll
  for (int j = 0; j < 4; j++)
    Wt[(size_t)(n0 + ty + j*8) * K + k0 + tx] = f2bf(tile[tx][ty + j*8]);
}

// ---------------- LayerNorm: src fp32 [rows][768] -> bf16 out
__global__ __launch_bounds__(256) void ln_kernel(const float* __restrict__ x,
                                                 const float* __restrict__ s,
                                                 const float* __restrict__ b,
                                                 unsigned short* __restrict__ out) {
  __shared__ float sh[4];
  const int row = blockIdx.x;
  const int tid = threadIdx.x;
  const float* xr = x + (size_t)row * HH;
  float v[3];
  float sum = 0.f;
  #pragma unroll
  for (int j = 0; j < 3; j++) { v[j] = xr[tid + j*256]; sum += v[j]; }
  sum = block_sum256(sum, sh);
  const float mu = sum * (1.f/768.f);
  float ss = 0.f;
  #pragma unroll
  for (int j = 0; j < 3; j++) { float d = v[j] - mu; ss += d*d; }
  ss = block_sum256(ss, sh);
  const float rstd = rsqrtf(ss * (1.f/768.f) + 1e-5f);
  #pragma unroll
  for (int j = 0; j < 3; j++) {
    int col = tid + j*256;
    out[(size_t)row * HH + col] = f2bf((v[j]-mu)*rstd*s[col] + b[col]);
  }
}

// ---------------- 128^2 2-phase GEMM (all four GEMM shapes; proven fastest structure)
// EPI 0: bf16 out. EPI 1: +bias, gelu, bf16 out. EPI 2: +bias +resIn (fp32), fp32 out.
template<int EPI>
__global__ __launch_bounds__(256) void gemm_kernel(const unsigned short* __restrict__ A,
                                                   const unsigned short* __restrict__ Bt,
                                                   unsigned short* __restrict__ outB,
                                                   float* __restrict__ outF,
                                                   const float* __restrict__ resIn,
                                                   const float* __restrict__ bias,
                                                   int Ng, int Kg, int nx) {
  __shared__ unsigned short a_lds[2][128*64];
  __shared__ unsigned short b_lds[2][128*64];
  const int tid = threadIdx.x;
  const int w = tid >> 6, l = tid & 63;
  const int nwg = gridDim.x;
  const int lin = blockIdx.x;
  const int L = (lin & 7) * (nwg >> 3) + (lin >> 3);
  const int m0 = (L / nx) * 128, n0 = (L % nx) * 128;

  const int wr = (w >> 1) * 64, wc = (w & 1) * 64;
  const int l15 = l & 15, lhi = l >> 4;
  const int srow = w*32 + (l >> 3);
  const int schunk = (l & 7) ^ (l >> 3);
  const int scol = schunk << 3;

  f32x4 acc[4][4] = {};
  const int nk = Kg >> 6;
  int cur = 0;

  #pragma unroll
  for (int i = 0; i < 4; i++) {
    const unsigned short* gsa = A  + (size_t)(m0 + srow + i*8)*Kg + scol;
    const unsigned short* gsb = Bt + (size_t)(n0 + srow + i*8)*Kg + scol;
    __builtin_amdgcn_global_load_lds(GLOBAL_AS(gsa), LDS_AS(&a_lds[0][w*2048 + i*512]), 16, 0, 0);
    __builtin_amdgcn_global_load_lds(GLOBAL_AS(gsb), LDS_AS(&b_lds[0][w*2048 + i*512]), 16, 0, 0);
  }
  __syncthreads();

  for (int t = 0; t < nk; t++) {
    if (t + 1 < nk) {
      const int ks = (t + 1) << 6;
      #pragma unroll
      for (int i = 0; i < 4; i++) {
        const unsigned short* gsa = A  + (size_t)(m0 + srow + i*8)*Kg + ks + scol;
        const unsigned short* gsb = Bt + (size_t)(n0 + srow + i*8)*Kg + ks + scol;
        __builtin_amdgcn_global_load_lds(GLOBAL_AS(gsa), LDS_AS(&a_lds[cur^1][w*2048 + i*512]), 16, 0, 0);
        __builtin_amdgcn_global_load_lds(GLOBAL_AS(gsb), LDS_AS(&b_lds[cur^1][w*2048 + i*512]), 16, 0, 0);
      }
    }
    const unsigned short* ab = &a_lds[cur][0];
    const unsigned short* bb = &b_lds[cur][0];
    #pragma unroll
    for (int kb = 0; kb < 2; kb++) {
      bf16x8 af[4], bfr[4];
      const int rc = (kb*4 + lhi) ^ (l15 & 7);
      #pragma unroll
      for (int rb = 0; rb < 4; rb++)
        af[rb] = *(const bf16x8*)&ab[(wr + rb*16 + l15)*64 + (rc << 3)];
      #pragma unroll
      for (int nb = 0; nb < 4; nb++)
        bfr[nb] = *(const bf16x8*)&bb[(wc + nb*16 + l15)*64 + (rc << 3)];
      #pragma unroll
      for (int rb = 0; rb < 4; rb++)
        #pragma unroll
        for (int nb = 0; nb < 4; nb++)
          acc[rb][nb] = mfma16(af[rb], bfr[nb], acc[rb][nb]);
    }
    __syncthreads();
    cur ^= 1;
  }

  const int lr = lhi << 2;
  #pragma unroll
  for (int rb = 0; rb < 4; rb++)
    #pragma unroll
    for (int nb = 0; nb < 4; nb++) {
      const int row = m0 + wr + rb*16 + lr;
      const int col = n0 + wc + nb*16 + l15;
      #pragma unroll
      for (int r = 0; r < 4; r++) {
        float v = acc[rb][nb][r];
        const size_t off = (size_t)(row + r)*Ng + col;
        if (EPI == 0) {
          outB[off] = f2bf(v);
        } else if (EPI == 1) {
          v += bias[col];
          float u = 0.79788456080287f * v * (1.f + 0.044715f * v * v);
          u = fminf(u, 15.f);
          float e = fast_exp2(u * 2.88539008177793f);   // e^{2u}
          float th = 1.f - 2.f / (e + 1.f);
          v = 0.5f * v * (1.f + th);
          outB[off] = f2bf(v);
        } else {
          v += bias[col] + resIn[off];
          outF[off] = v;
        }
      }
    }
}

// ---------------- bias precompute: biasP[b][q][k] = log2e*(ov_emb[min(ov,10)] - alpha*clip(lp[b][k]))
__global__ __launch_bounds__(256) void biasprep_kernel(const int* __restrict__ overlap,
                                                       const float* __restrict__ lp,
                                                       const float* __restrict__ ov_emb,
                                                       const float* __restrict__ ht_alpha,
                                                       float* __restrict__ biasP) {
  __shared__ float oe[11];
  if (threadIdx.x < 11) oe[threadIdx.x] = ov_emb[threadIdx.x] * 1.44269504088896f;
  __syncthreads();
  const float aL = ht_alpha[0] * 1.44269504088896f;
  const size_t base = ((size_t)blockIdx.x * 256 + threadIdx.x) * 4;
  const int b = (int)(base >> 20);
  const int k0 = (int)(base & 1023);
  int4 ov = *(const int4*)&overlap[base];
  float4 lv = *(const float4*)&lp[b * MM + k0];
  float4 o4;
  {
    int t0 = ov.x < 10 ? ov.x : 10; float c0 = fminf(fmaxf(lv.x, -30.f), 0.f); o4.x = oe[t0] - aL*c0;
    int t1 = ov.y < 10 ? ov.y : 10; float c1 = fminf(fmaxf(lv.y, -30.f), 0.f); o4.y = oe[t1] - aL*c1;
    int t2 = ov.z < 10 ? ov.z : 10; float c2 = fminf(fmaxf(lv.z, -30.f), 0.f); o4.z = oe[t2] - aL*c2;
    int t3 = ov.w < 10 ? ov.w : 10; float c3 = fminf(fmaxf(lv.w, -30.f), 0.f); o4.w = oe[t3] - aL*c3;
  }
  *(float4*)&biasP[base] = o4;
}

// ---------------- flash attention, swapped operands (S^T / O^T), exp2-domain softmax
// R5 structure (best measured): single barrier per K-tile, dbuf K (gload_lds) +
// dbuf V (reg-carried one iteration), bias prefetch at iteration top, cvt_pk
// packing, defer-max, setprio. 48KB LDS, natural VGPR (~124).
__global__ __launch_bounds__(256) void attn_kernel(const unsigned short* __restrict__ qkv,
                                                   const float* __restrict__ biasP,
                                                   unsigned short* __restrict__ obuf) {
  __shared__ unsigned short k_lds[2][64*64];
  __shared__ unsigned short v_lds[2][64*64];
  __shared__ unsigned short pmat[4][32*64];

  const int tid = threadIdx.x;
  const int w = tid >> 6, l = tid & 63;
  const int lin = blockIdx.x;
  const int L = (lin & 7) * 96 + (lin >> 3);    // bijective (768 % 8 == 0)
  const int h = L % 12;
  const int qb = (L / 12) & 7;
  const int b = L / 96;
  const int q0w = qb*128 + w*32;
  const int l15 = l & 15, lhi = l >> 4;
  const float SC = 0.125f * 1.44269504088896f;

  const int kr_s = l >> 3;
  const int schunk = (l & 7) ^ kr_s;
  const int dc = (l & 7) << 3;

  bf16x8 qf[2][2];
  #pragma unroll
  for (int rb = 0; rb < 2; rb++)
    #pragma unroll
    for (int kb = 0; kb < 2; kb++)
      qf[rb][kb] = *(const bf16x8*)&qkv[(size_t)(b*MM + q0w + rb*16 + l15)*H3 + h*HDIM + kb*32 + lhi*8];

  const float* brow[2];
  #pragma unroll
  for (int rb = 0; rb < 2; rb++)
    brow[rb] = biasP + (size_t)(b*MM + q0w + rb*16 + l15) * MM;

  f32x4 oacc[4][2] = {};
  float mrow[2] = {-INFINITY, -INFINITY};
  float lrow[2] = {0.f, 0.f};

  // prologue: K0 -> LDS, V0 -> LDS (via regs), V1 -> vcur (held one iteration)
  bf16x8 vcur[2];
  {
    #pragma unroll
    for (int i = 0; i < 2; i++) {
      const unsigned short* g = qkv + (size_t)(b*MM + i*32 + w*8 + kr_s)*H3 + h*HDIM + HH + schunk*8;
      __builtin_amdgcn_global_load_lds(GLOBAL_AS(g), LDS_AS(&k_lds[0][(i*32 + w*8)*64]), 16, 0, 0);
    }
    bf16x8 vr[2];
    #pragma unroll
    for (int i = 0; i < 2; i++)
      vr[i] = *(const bf16x8*)&qkv[(size_t)(b*MM + i*32 + w*8 + kr_s)*H3 + h*HDIM + 2*HH + dc];
    #pragma unroll
    for (int i = 0; i < 2; i++) {
      int kr = i*32 + w*8 + kr_s;
      #pragma unroll
      for (int j = 0; j < 8; j++) {
        int key = ((((dc >> 3) & 7) ^ j) & 7) << 3;
        v_lds[0][(dc + j)*64 + (kr ^ key)] = (unsigned short)(short)vr[i][j];
      }
    }
    #pragma unroll
    for (int i = 0; i < 2; i++)
      vcur[i] = *(const bf16x8*)&qkv[(size_t)(b*MM + 64 + i*32 + w*8 + kr_s)*H3 + h*HDIM + 2*HH + dc];
    __syncthreads();
  }

  for (int kt = 0; kt < 16; kt++) {
    const int cur = kt & 1;
    const int kbase = kt * 64;

    // ---- top-of-iteration staging (buffers cur^1 freed by previous iter's barrier)
    if (kt < 15) {
      // write V(kt+1) from regs (loaded one full iteration ago)
      #pragma unroll
      for (int i = 0; i < 2; i++) {
        int kr = i*32 + w*8 + kr_s;
        #pragma unroll
        for (int j = 0; j < 8; j++) {
          int key = ((((dc >> 3) & 7) ^ j) & 7) << 3;
          v_lds[cur^1][(dc + j)*64 + (kr ^ key)] = (unsigned short)(short)vcur[i][j];
        }
      }
      // issue K(kt+1) async copy
      const int nbase = kbase + 64;
      #pragma unroll
      for (int i = 0; i < 2; i++) {
        const unsigned short* g = qkv + (size_t)(b*MM + nbase + i*32 + w*8 + kr_s)*H3 + h*HDIM + HH + schunk*8;
        __builtin_amdgcn_global_load_lds(GLOBAL_AS(g), LDS_AS(&k_lds[cur^1][(i*32 + w*8)*64]), 16, 0, 0);
      }
    }
    if (kt < 14) {
      const int n2 = kbase + 128;
      #pragma unroll
      for (int i = 0; i < 2; i++)
        vcur[i] = *(const bf16x8*)&qkv[(size_t)(b*MM + n2 + i*32 + w*8 + kr_s)*H3 + h*HDIM + 2*HH + dc];
    }
    // bias prefetch for this tile
    f32x4 bregs[4][2];
    #pragma unroll
    for (int nb = 0; nb < 4; nb++)
      #pragma unroll
      for (int rb = 0; rb < 2; rb++)
        bregs[nb][rb] = *(const f32x4*)&brow[rb][kbase + nb*16 + lhi*4];

    // ---- S^T[kk][q] = K·Q^T
    f32x4 sacc[4][2] = {};
    __builtin_amdgcn_s_setprio(1);
    #pragma unroll
    for (int kb = 0; kb < 2; kb++) {
      bf16x8 ak[4];
      #pragma unroll
      for (int nb = 0; nb < 4; nb++) {
        int n = nb*16 + l15;
        ak[nb] = *(const bf16x8*)&k_lds[cur][n*64 + ((kb*32 + lhi*8) ^ ((n & 7) << 3))];
      }
      #pragma unroll
      for (int nb = 0; nb < 4; nb++)
        #pragma unroll
        for (int rb = 0; rb < 2; rb++)
          sacc[nb][rb] = mfma16(ak[nb], qf[rb][kb], sacc[nb][rb]);
    }
    __builtin_amdgcn_s_setprio(0);

    // scale (log2 domain) + bias (prefetched)
    #pragma unroll
    for (int nb = 0; nb < 4; nb++)
      #pragma unroll
      for (int rb = 0; rb < 2; rb++)
        #pragma unroll
        for (int r = 0; r < 4; r++)
          sacc[nb][rb][r] = fmaf(sacc[nb][rb][r], SC, bregs[nb][rb][r]);

    // lane-local online softmax with defer-max
    float corrf[2];
    int defer[2];
    #pragma unroll
    for (int rb = 0; rb < 2; rb++) {
      float pm = sacc[0][rb][0];
      #pragma unroll
      for (int nb = 0; nb < 4; nb++)
        #pragma unroll
        for (int r = 0; r < 4; r++)
          pm = fmaxf(pm, sacc[nb][rb][r]);
      pm = fmaxf(pm, __shfl_xor(pm, 16));
      pm = fmaxf(pm, __shfl_xor(pm, 32));
      defer[rb] = __all(pm - mrow[rb] <= 8.0f);
      const float mnew = defer[rb] ? mrow[rb] : fmaxf(mrow[rb], pm);
      const float corr = defer[rb] ? 1.0f : fast_exp2(mrow[rb] - mnew);
      float rs = 0.f;
      #pragma unroll
      for (int nb = 0; nb < 4; nb++)
        #pragma unroll
        for (int r = 0; r < 4; r++) {
          float p = fast_exp2(sacc[nb][rb][r] - mnew);
          sacc[nb][rb][r] = p;
          rs += p;
        }
      rs += __shfl_xor(rs, 16);
      rs += __shfl_xor(rs, 32);
      mrow[rb] = mnew;
      lrow[rb] = lrow[rb]*corr + rs;
      corrf[rb] = corr;
    }
    #pragma unroll
    for (int rb = 0; rb < 2; rb++)
      if (!defer[rb]) {          // wave-uniform branch
        #pragma unroll
        for (int db = 0; db < 4; db++)
          #pragma unroll
          for (int r = 0; r < 4; r++)
            oacc[db][rb][r] *= corrf[rb];
      }

    // P^T tile to per-wave LDS as [q][kk] (packed via cvt_pk)
    unsigned short* pw = &pmat[w][0];
    #pragma unroll
    for (int nb = 0; nb < 4; nb++)
      #pragma unroll
      for (int rb = 0; rb < 2; rb++) {
        uint2 pk;
        pk.x = cvt_pk_bf16(sacc[nb][rb][0], sacc[nb][rb][1]);
        pk.y = cvt_pk_bf16(sacc[nb][rb][2], sacc[nb][rb][3]);
        *(uint2*)&pw[(rb*16 + l15)*64 + ((nb*16 + lhi*4) ^ ((l15 & 7) << 3))] = pk;
      }

    // O^T += V^T · P^T
    __builtin_amdgcn_s_setprio(1);
    #pragma unroll
    for (int kb = 0; kb < 2; kb++) {
      bf16x8 pb[2];
      #pragma unroll
      for (int rb = 0; rb < 2; rb++)
        pb[rb] = *(const bf16x8*)&pw[(rb*16 + l15)*64 + ((kb*32 + lhi*8) ^ ((l15 & 7) << 3))];
      bf16x8 av[4];
      #pragma unroll
      for (int db = 0; db < 4; db++) {
        int d = db*16 + l15;
        int key = ((((d >> 3) & 7) ^ (d & 7)) & 7) << 3;
        av[db] = *(const bf16x8*)&v_lds[cur][d*64 + ((kb*32 + lhi*8) ^ key)];
      }
      #pragma unroll
      for (int db = 0; db < 4; db++)
        #pragma unroll
        for (int rb = 0; rb < 2; rb++)
          oacc[db][rb] = mfma16(av[db], pb[rb], oacc[db][rb]);
    }
    __builtin_amdgcn_s_setprio(0);

    __syncthreads();   // single barrier: drains K gload + V reg-load; frees cur bufs
  }

  // epilogue: normalize, transpose via per-wave LDS, coalesced write
  float inv[2] = { 1.f / lrow[0], 1.f / lrow[1] };
  unsigned short* pw = &pmat[w][0];
  #pragma unroll
  for (int db = 0; db < 4; db++)
    #pragma unroll
    for (int rb = 0; rb < 2; rb++) {
      uint2 pk;
      pk.x = cvt_pk_bf16(oacc[db][rb][0] * inv[rb], oacc[db][rb][1] * inv[rb]);
      pk.y = cvt_pk_bf16(oacc[db][rb][2] * inv[rb], oacc[db][rb][3] * inv[rb]);
      *(uint2*)&pw[(rb*16 + l15)*64 + ((db*16 + lhi*4) ^ ((l15 & 7) << 3))] = pk;
    }
  #pragma unroll
  for (int rep = 0; rep < 4; rep++) {
    int qq = rep*8 + (l >> 3);
    int d0 = (l & 7) << 3;
    bf16x8 vv = *(const bf16x8*)&pw[qq*64 + (d0 ^ ((qq & 7) << 3))];
    *(bf16x8*)&obuf[(size_t)(b*MM + q0w + qq)*HH + h*HDIM + d0] = vv;
  }
}

// ---------------- HT weights
__global__ __launch_bounds__(256) void htw_kernel(const float* __restrict__ lp,
                                                  float* __restrict__ w_ht) {
  __shared__ float sh[4];
  const int b = blockIdx.x, tid = threadIdx.x;
  float vals[4];
  float mx = -INFINITY;
  #pragma unroll
  for (int j = 0; j < 4; j++) {
    float lv = lp[b*MM + tid + j*256];
    float lc = fminf(fmaxf(lv, -30.f), 0.f);
    vals[j] = -lc;
    mx = fmaxf(mx, vals[j]);
  }
  mx = block_max256(mx, sh);
  float se = 0.f;
  #pragma unroll
  for (int j = 0; j < 4; j++) { vals[j] = expf(vals[j] - mx); se += vals[j]; }
  se = block_sum256(se, sh);
  const float inv = 1.f / se;
  #pragma unroll
  for (int j = 0; j < 4; j++) w_ht[b*MM + tid + j*256] = vals[j] * inv;
}

// ---------------- final LN + weighted partial sums
__global__ __launch_bounds__(256) void final_partial_kernel(const float* __restrict__ xbuf,
                                                            const float* __restrict__ lno_s,
                                                            const float* __restrict__ lno_b,
                                                            const float* __restrict__ w_ht,
                                                            float* __restrict__ part) {
  __shared__ float sh[4];
  const int b = blockIdx.x >> 4;
  const int chunk = blockIdx.x & 15;
  const int tid = threadIdx.x;
  float acc[3] = {0.f, 0.f, 0.f};
  float sc[3], bc[3];
  #pragma unroll
  for (int j = 0; j < 3; j++) { sc[j] = lno_s[tid + j*256]; bc[j] = lno_b[tid + j*256]; }
  for (int rr = 0; rr < 64; rr++) {
    const int tok = b*MM + chunk*64 + rr;
    const float* xr = xbuf + (size_t)tok * HH;
    float v[3]; float sum = 0.f;
    #pragma unroll
    for (int j = 0; j < 3; j++) { v[j] = xr[tid + j*256]; sum += v[j]; }
    sum = block_sum256(sum, sh);
    const float mu = sum * (1.f/768.f);
    float ss = 0.f;
    #pragma unroll
    for (int j = 0; j < 3; j++) { float d = v[j] - mu; ss += d*d; }
    ss = block_sum256(ss, sh);
    const float rstd = rsqrtf(ss * (1.f/768.f) + 1e-5f);
    const float wgt = w_ht[b*MM + chunk*64 + rr];
    #pragma unroll
    for (int j = 0; j < 3; j++) acc[j] += wgt * ((v[j]-mu)*rstd*sc[j] + bc[j]);
  }
  #pragma unroll
  for (int j = 0; j < 3; j++) part[(size_t)blockIdx.x * HH + tid + j*256] = acc[j];
}

__global__ __launch_bounds__(256) void final_reduce_kernel(const float* __restrict__ part,
                                                           float* __restrict__ out) {
  const int b = blockIdx.x;
  const int col = blockIdx.y*256 + threadIdx.x;
  float s = 0.f;
  #pragma unroll
  for (int c = 0; c < 16; c++) s += part[(size_t)(b*16 + c) * HH + col];
  out[b*HH + col] = s;
}

extern "C" void kernel_launch(void* const* d_in, const int* in_sizes, int n_in,
                              void* d_out, int out_size, void* d_ws, size_t ws_size,
                              hipStream_t stream) {
  (void)in_sizes; (void)n_in;
  const float* x      = (const float*)d_in[0];
  const int*   overlap= (const int*)d_in[1];
  const float* lp     = (const float*)d_in[2];
  const float* ln1_s  = (const float*)d_in[3];
  const float* ln1_b  = (const float*)d_in[4];
  const float* Wqkv   = (const float*)d_in[5];
  const float* Wout   = (const float*)d_in[6];
  const float* bout   = (const float*)d_in[7];
  const float* ln2_s  = (const float*)d_in[8];
  const float* ln2_b  = (const float*)d_in[9];
  const float* W1     = (const float*)d_in[10];
  const float* b1     = (const float*)d_in[11];
  const float* W2     = (const float*)d_in[12];
  const float* b2     = (const float*)d_in[13];
  const float* lno_s  = (const float*)d_in[14];
  const float* lno_b  = (const float*)d_in[15];
  const float* ov_emb = (const float*)d_in[16];
  const float* ht_alpha = (const float*)d_in[17];
  float* out = (float*)d_out;

  char* ws = (char*)d_ws;
  float*          xbuf  = (float*)(ws + 0);                    // 25165824 B
  unsigned short* lnout = (unsigned short*)(ws + 25165824);    // 12582912 B
  unsigned short* qkv   = (unsigned short*)(ws + 37748736);    // 37748736 B
  unsigned short* obuf  = (unsigned short*)(ws + 75497472);    // 12582912 B
  unsigned short* gbuf  = (unsigned short*)(ws + 88080384);    // 50331648 B
  unsigned short* wbuf  = (unsigned short*)(ws + 138412032);   //  4718592 B
  float*          w_ht  = (float*)(ws + 143130624);            //    32768 B
  float*          part  = (float*)(ws + 143163392);            //   393216 B
  const int prep_once = (ws_size >= (size_t)143556608 + (size_t)33554432);
  float*          biasP = prep_once ? (float*)(ws + 143556608) : (float*)gbuf;

  htw_kernel<<<BB, 256, 0, stream>>>(lp, w_ht);
  if (prep_once)
    biasprep_kernel<<<(BB*MM*MM/4)/256, 256, 0, stream>>>(overlap, lp, ov_emb, ht_alpha, biasP);

  for (int t = 0; t < TT; t++) {
    const float* res = (t == 0) ? x : xbuf;   // residual stream source (xbuf first
                                              // written by t=0 Wout epilogue)
    // --- attention block
    wconv_kernel<<<dim3(H3/32, HH/32), dim3(32, 8), 0, stream>>>(Wqkv + (size_t)t*HH*H3, wbuf, HH, H3);
    ln_kernel<<<NTOK, 256, 0, stream>>>(res, ln1_s + t*HH, ln1_b + t*HH, lnout);
    gemm_kernel<0><<<(H3/128)*(NTOK/128), 256, 0, stream>>>(lnout, wbuf, qkv, nullptr, nullptr, nullptr, H3, HH, H3/128);
    if (!prep_once)
      biasprep_kernel<<<(BB*MM*MM/4)/256, 256, 0, stream>>>(overlap, lp, ov_emb, ht_alpha, biasP);
    attn_kernel<<<BB*NHEAD*(MM/128), 256, 0, stream>>>(qkv, biasP, obuf);
    wconv_kernel<<<dim3(HH/32, HH/32), dim3(32, 8), 0, stream>>>(Wout + (size_t)t*HH*HH, wbuf, HH, HH);
    gemm_kernel<2><<<(HH/128)*(NTOK/128), 256, 0, stream>>>(obuf, wbuf, nullptr, xbuf, res, bout + t*HH, HH, HH, HH/128);
    // --- FFN block
    ln_kernel<<<NTOK, 256, 0, stream>>>(xbuf, ln2_s + t*HH, ln2_b + t*HH, lnout);
    wconv_kernel<<<dim3(H4/32, HH/32), dim3(32, 8), 0, stream>>>(W1 + (size_t)t*HH*H4, wbuf, HH, H4);
    gemm_kernel<1><<<(H4/128)*(NTOK/128), 256, 0, stream>>>(lnout, wbuf, gbuf, nullptr, nullptr, b1 + t*H4, H4, HH, H4/128);
    wconv_kernel<<<dim3(HH/32, H4/32), dim3(32, 8), 0, stream>>>(W2 + (size_t)t*H4*HH, wbuf, H4, HH);
    gemm_kernel<2><<<(HH/128)*(NTOK/128), 256, 0, stream>>>(gbuf, wbuf, nullptr, xbuf, xbuf, b2 + t*HH, HH, H4, HH/128);
  }

  final_partial_kernel<<<BB*16, 256, 0, stream>>>(xbuf, lno_s, lno_b, w_ht, part);
  final_reduce_kernel<<<dim3(BB, 3), 256, 0, stream>>>(part, out);

  (void)out_size;
}